// Round 12
// baseline (42.858 us; speedup 1.0000x reference)
//
#include <hip/hip_runtime.h>
#include <math.h>

// FrequencyAdaptiveNorm: multi-scale (w=5,10,20) centered sliding-window
// normalization over L, softmax-weighted fusion.
// x: (B=32, L=2048, F=256) f32, weights: (3,) f32, out: same shape.
//
// v12: SINGLE-ASSIGNMENT flat delay array val[52], macro-unrolled steps.
// v10/v11 post-mortem: the circular slot[(t+k)&31] overwrite pattern
// spilled ~8B/thread even with constant indices (WRITE_SIZE 69504 vs
// 65536) under the (256,8) 64-VGPR cap. Here every val[m] is written
// exactly once (step t inserts val[t+30], reads val[t+0..20]) -> pure SSA,
// ~31 floats live; launch_bounds(256,6) gives 85-VGPR headroom. Load is
// consumed 10 steps after issue (~600 issue-cycles) -> L2/L3 latency
// covered inside one wave. Edge blocks (2/64) keep the checked ring path.

#define B_ 32
#define L_ 2048
#define F_ 256
#define TL 32             // L-chunk per block; grid = (64, 32)
#define PRE 30            // prefilled entries m = 0..29
#define NV (TL + 20)      // 52 entries: val[m] = x[l0-10+m]

#define RSQ(x) __builtin_amdgcn_rsqf(x)   // single v_rsq_f32, ~1 ulp

__device__ __forceinline__ float fin(float v) {
    return isfinite(v) ? v : 0.0f;   // nan_to_num(nan=0, +inf=0, -inf=0)
}

// one step; T must be a constant expression 0..TL-1
#define STEP(T)                                                                \
  {                                                                            \
    constexpr int t_ = (T);                                                    \
    if constexpr (t_ + PRE < NV) {                                             \
      val[t_ + PRE] = fin(xr[(t_ + PRE) * F_]);   /* used 10 steps later */    \
    }                                                                          \
    const float xc = val[t_ + 10];                                             \
    float acc;                                                                 \
    {                                                                          \
      const float mean = s5 * 0.2f, mean2 = q5 * 0.2f;                         \
      const float var  = fmaxf(fmaf(-mean, mean, mean2), 0.0f);                \
      acc = ws5 * ((xc - mean) * RSQ(var + eps));                              \
    }                                                                          \
    {                                                                          \
      const float mean = s10 * 0.1f, mean2 = q10 * 0.1f;                       \
      const float var  = fmaxf(fmaf(-mean, mean, mean2), 0.0f);                \
      acc = fmaf(ws10, (xc - mean) * RSQ(var + eps), acc);                     \
    }                                                                          \
    {                                                                          \
      const float mean = s20 * 0.05f, mean2 = q20 * 0.05f;                     \
      const float var  = fmaxf(fmaf(-mean, mean, mean2), 0.0f);                \
      acc = fmaf(ws20, (xc - mean) * RSQ(var + eps), acc);                     \
    }                                                                          \
    obr[t_ * F_] = acc;                                                        \
    if constexpr (t_ < TL - 1) {                                               \
      {                                                                        \
        const float a = val[t_ + 13], r = val[t_ + 8];                         \
        const float d = a - r, p = a + r;                                      \
        s5 += d; q5 = fmaf(d, p, q5);                                          \
      }                                                                        \
      {                                                                        \
        const float a = val[t_ + 15], r = val[t_ + 5];                         \
        const float d = a - r, p = a + r;                                      \
        s10 += d; q10 = fmaf(d, p, q10);                                       \
      }                                                                        \
      {                                                                        \
        const float a = val[t_ + 20], r = val[t_];                             \
        const float d = a - r, p = a + r;                                      \
        s20 += d; q20 = fmaf(d, p, q20);                                       \
      }                                                                        \
    }                                                                          \
  }

#define STEP4(A)  STEP(A) STEP((A) + 1) STEP((A) + 2) STEP((A) + 3)
#define STEP16(A) STEP4(A) STEP4((A) + 4) STEP4((A) + 8) STEP4((A) + 12)

// ---------------- interior: single-assignment delay array ------------------
__device__ __forceinline__ void run_interior(const float* __restrict__ xb,
                                             float* __restrict__ ob,
                                             const int l0,
                                             const float ws5, const float ws10,
                                             const float ws20) {
    const float eps = 1e-5f;
    const float* xr  = xb + (l0 - 10) * F_;   // xr[m*F_] = x[l0-10+m]
    float*       obr = ob + l0 * F_;

    float val[NV];
#pragma unroll
    for (int m = 0; m < PRE; ++m) val[m] = fin(xr[m * F_]);

    // running sums at j=l0: w20 = m 0..19, w10 = m 5..14, w5 = m 8..12
    float s5 = 0.f, q5 = 0.f, s10 = 0.f, q10 = 0.f, s20 = 0.f, q20 = 0.f;
#pragma unroll
    for (int m = 0; m < 20; ++m) { s20 += val[m]; q20 = fmaf(val[m], val[m], q20); }
#pragma unroll
    for (int m = 5; m < 15; ++m) { s10 += val[m]; q10 = fmaf(val[m], val[m], q10); }
#pragma unroll
    for (int m = 8; m < 13; ++m) { s5  += val[m]; q5  = fmaf(val[m], val[m], q5);  }

    // 32 macro-expanded steps — all indices constant, every val[m] written once
    STEP16(0)
    STEP16(16)
}

// ---------------- edge: checked shifting-ring path (blocks 0, 63) ----------
__device__ __forceinline__ void run_edge(const float* __restrict__ xb,
                                         float* __restrict__ ob,
                                         const int l0,
                                         const float ws5, const float ws10,
                                         const float ws20) {
    const float eps = 1e-5f;
    float ring[21];
#pragma unroll
    for (int d = 0; d < 21; ++d) {
        const int l = l0 - 10 + d;
        ring[d] = ((unsigned)l < (unsigned)L_) ? fin(xb[l * F_]) : 0.0f;
    }
    float s5 = 0.f, q5 = 0.f, s10 = 0.f, q10 = 0.f, s20 = 0.f, q20 = 0.f;
#pragma unroll
    for (int d = 0; d < 20; ++d) { s20 += ring[d]; q20 = fmaf(ring[d], ring[d], q20); }
#pragma unroll
    for (int d = 5; d < 15; ++d) { s10 += ring[d]; q10 = fmaf(ring[d], ring[d], q10); }
#pragma unroll
    for (int d = 8; d < 13; ++d) { s5  += ring[d]; q5  = fmaf(ring[d], ring[d], q5);  }

#pragma unroll
    for (int t = 0; t < TL; ++t) {
        const int j = l0 + t;
        const int ln = j + 11;
        const float vnew = ((unsigned)ln < (unsigned)L_) ? fin(xb[ln * F_]) : 0.0f;

        const float xc = ring[10];
        float acc = 0.0f;
        if (j >= 2 && j <= L_ - 3) {
            const float mean = s5 * 0.2f, mean2 = q5 * 0.2f;
            const float var  = fmaxf(fmaf(-mean, mean, mean2), 0.0f);
            acc = fmaf(ws5, (xc - mean) * RSQ(var + eps), acc);
        }
        if (j >= 5 && j <= L_ - 5) {
            const float mean = s10 * 0.1f, mean2 = q10 * 0.1f;
            const float var  = fmaxf(fmaf(-mean, mean, mean2), 0.0f);
            acc = fmaf(ws10, (xc - mean) * RSQ(var + eps), acc);
        }
        if (j >= 10 && j <= L_ - 10) {
            const float mean = s20 * 0.05f, mean2 = q20 * 0.05f;
            const float var  = fmaxf(fmaf(-mean, mean, mean2), 0.0f);
            acc = fmaf(ws20, (xc - mean) * RSQ(var + eps), acc);
        }
        ob[j * F_] = acc;

        { const float a = ring[13], r = ring[8];  const float d = a - r, p = a + r; s5  += d; q5  = fmaf(d, p, q5);  }
        { const float a = ring[15], r = ring[5];  const float d = a - r, p = a + r; s10 += d; q10 = fmaf(d, p, q10); }
        { const float a = ring[20], r = ring[0];  const float d = a - r, p = a + r; s20 += d; q20 = fmaf(d, p, q20); }

#pragma unroll
        for (int d = 0; d < 20; ++d) ring[d] = ring[d + 1];
        ring[20] = vnew;
    }
}

__global__ __launch_bounds__(256, 6)
void fan_kernel(const float* __restrict__ x,
                const float* __restrict__ w,
                float* __restrict__ out) {
    const int f  = threadIdx.x;           // 0..255 == F
    const int b  = blockIdx.y;
    const int l0 = blockIdx.x * TL;
    const float* xb = x   + (size_t)b * L_ * F_ + f;
    float*       ob = out + (size_t)b * L_ * F_ + f;

    // softmax over the 3 fusion logits (uniform across threads)
    const float w0 = w[0], w1 = w[1], w2 = w[2];
    const float m  = fmaxf(w0, fmaxf(w1, w2));
    const float e0 = expf(w0 - m), e1 = expf(w1 - m), e2 = expf(w2 - m);
    const float inv = 1.0f / (e0 + e1 + e2);
    const float ws5 = e0 * inv, ws10 = e1 * inv, ws20 = e2 * inv;

    // interior blocks 1..62: loads span [l0-10, l0+41] -> in range, and all
    // three window validity ranges cover every j in the chunk.
    if (blockIdx.x != 0 && blockIdx.x != gridDim.x - 1)
        run_interior(xb, ob, l0, ws5, ws10, ws20);
    else
        run_edge(xb, ob, l0, ws5, ws10, ws20);
}

extern "C" void kernel_launch(void* const* d_in, const int* in_sizes, int n_in,
                              void* d_out, int out_size, void* d_ws, size_t ws_size,
                              hipStream_t stream) {
    const float* x = (const float*)d_in[0];
    const float* w = (const float*)d_in[1];
    float* out = (float*)d_out;
    (void)in_sizes; (void)n_in; (void)out_size; (void)d_ws; (void)ws_size;

    dim3 grid(L_ / TL, B_);   // (64, 32) = 2048 blocks
    dim3 block(F_);           // 256 threads, one per feature column
    hipLaunchKernelGGL(fan_kernel, grid, block, 0, stream, x, w, out);
}

// Round 13
// 32.969 us; speedup vs baseline: 1.2999x; 1.2999x over previous
//
#include <hip/hip_runtime.h>
#include <math.h>

// FrequencyAdaptiveNorm: multi-scale (w=5,10,20) centered sliding-window
// normalization over L, softmax-weighted fusion.
// x: (B=32, L=2048, F=256) f32, weights: (3,) f32, out: same shape.
//
// v13 = v9 (best, 32.5us; ring[24], TL=32, launch_bounds(256,8)) +
//  (a) algebraic norm: (xc-mean)*rsqrt(var+eps) == n*rsq(P) with
//      P = max(q*W - s^2 + W^2*eps, W^2*eps), n = W*xc - s  (W = window)
//      -> 6 VALU + 1 trans per scale (was 8+1), exact var>=0 clamp kept.
//  (b) nontemporal stores: out is write-once -> bypass L2, keep it for the
//      input halo.
// v12 lessons: ring shift was ALREADY renamed (zero-mov rewrite changed
// nothing); launch_bounds 2nd arg correlates with achieved occupancy ->
// pinned at (256,8).

#define B_ 32
#define L_ 2048
#define F_ 256
#define TL 32     // L-chunk per block; grid = (64, 32) = 2048 blocks
#define NR 24     // ring size; ring[d] = x[j-10+d]; insert at d=23 (j+14)

#define RSQ(x) __builtin_amdgcn_rsqf(x)   // single v_rsq_f32, ~1 ulp

__device__ __forceinline__ float fin(float v) {
    return isfinite(v) ? v : 0.0f;   // nan_to_num(nan=0, +inf=0, -inf=0)
}

// one scale's contribution: W = window width, C = W*W*eps
__device__ __forceinline__ float scale_term(const float xc, const float s,
                                            const float q, const float W,
                                            const float C) {
    float P = fmaf(-s, s, C);      // C - s^2
    P = fmaf(q, W, P);             // q*W - s^2 + W^2*eps  (= W^2*(var+eps))
    P = fmaxf(P, C);               // == W^2*(max(var,0)+eps)
    const float n = fmaf(W, xc, -s);   // W*(xc - mean)
    return n * RSQ(P);             // (xc-mean)*rsqrt(var+eps)
}

template <bool CHECKED>
__device__ __forceinline__ void run_chunk(const float* __restrict__ xb,
                                          float* __restrict__ ob,
                                          const int l0,
                                          const float ws5, const float ws10,
                                          const float ws20) {
    const float C5  = 25.0f  * 1e-5f;
    const float C10 = 100.0f * 1e-5f;
    const float C20 = 400.0f * 1e-5f;

    // delay line: ring[d] = x[l0-10+d], d = 0..NR-1
    float ring[NR];
#pragma unroll
    for (int d = 0; d < NR; ++d) {
        const int l = l0 - 10 + d;
        float v;
        if (CHECKED)
            v = ((unsigned)l < (unsigned)L_) ? xb[l * F_] : 0.0f;
        else
            v = xb[l * F_];
        ring[d] = fin(v);
    }

    // running sums at j=l0: w5=ring[8..12], w10=ring[5..14], w20=ring[0..19]
    float s5 = 0.f, q5 = 0.f, s10 = 0.f, q10 = 0.f, s20 = 0.f, q20 = 0.f;
#pragma unroll
    for (int d = 0; d < 20; ++d) { s20 += ring[d]; q20 = fmaf(ring[d], ring[d], q20); }
#pragma unroll
    for (int d = 5; d < 15; ++d) { s10 += ring[d]; q10 = fmaf(ring[d], ring[d], q10); }
#pragma unroll
    for (int d = 8; d < 13; ++d) { s5  += ring[d]; q5  = fmaf(ring[d], ring[d], q5);  }

#pragma unroll
    for (int t = 0; t < TL; ++t) {
        const int j = l0 + t;

        // ring-insert load, 4 iterations ahead of first use
        float vnew;
        if (CHECKED) {
            const int ln = j + 14;
            vnew = ((unsigned)ln < (unsigned)L_) ? fin(xb[ln * F_]) : 0.0f;
        } else {
            vnew = fin(xb[(j + 14) * F_]);
        }

        const float xc = ring[10];
        float acc = 0.0f;

        if (!CHECKED || (j >= 2 && j <= L_ - 3))            // w=5
            acc = fmaf(ws5,  scale_term(xc, s5,  q5,  5.0f,  C5),  acc);
        if (!CHECKED || (j >= 5 && j <= L_ - 5))            // w=10
            acc = fmaf(ws10, scale_term(xc, s10, q10, 10.0f, C10), acc);
        if (!CHECKED || (j >= 10 && j <= L_ - 10))          // w=20
            acc = fmaf(ws20, scale_term(xc, s20, q20, 20.0f, C20), acc);

        __builtin_nontemporal_store(acc, &ob[j * F_]);   // write-once output

        // slide windows j -> j+1:  s += a-r;  q += (a-r)(a+r)
        {
            const float a = ring[13], r = ring[8];
            const float d = a - r, p = a + r;
            s5 += d; q5 = fmaf(d, p, q5);
        }
        {
            const float a = ring[15], r = ring[5];
            const float d = a - r, p = a + r;
            s10 += d; q10 = fmaf(d, p, q10);
        }
        {
            const float a = ring[20], r = ring[0];
            const float d = a - r, p = a + r;
            s20 += d; q20 = fmaf(d, p, q20);
        }

        // shift delay line (compiler renames; v12 proved zero real movs)
#pragma unroll
        for (int d = 0; d < NR - 1; ++d) ring[d] = ring[d + 1];
        ring[NR - 1] = vnew;
    }
}

__global__ __launch_bounds__(256, 8)
void fan_kernel(const float* __restrict__ x,
                const float* __restrict__ w,
                float* __restrict__ out) {
    const int f  = threadIdx.x;           // 0..255 == F
    const int b  = blockIdx.y;
    const int l0 = blockIdx.x * TL;
    const float* xb = x   + (size_t)b * L_ * F_ + f;
    float*       ob = out + (size_t)b * L_ * F_ + f;

    // softmax over the 3 fusion logits (uniform across threads)
    const float w0 = w[0], w1 = w[1], w2 = w[2];
    const float m  = fmaxf(w0, fmaxf(w1, w2));
    const float e0 = expf(w0 - m), e1 = expf(w1 - m), e2 = expf(w2 - m);
    const float inv = 1.0f / (e0 + e1 + e2);
    const float ws5 = e0 * inv, ws10 = e1 * inv, ws20 = e2 * inv;

    // interior blocks 1..62: loads span [l0-10, l0+TL+13] -> in range, and
    // all three window validity ranges cover every j in the chunk.
    if (blockIdx.x != 0 && blockIdx.x != gridDim.x - 1)
        run_chunk<false>(xb, ob, l0, ws5, ws10, ws20);
    else
        run_chunk<true>(xb, ob, l0, ws5, ws10, ws20);
}

extern "C" void kernel_launch(void* const* d_in, const int* in_sizes, int n_in,
                              void* d_out, int out_size, void* d_ws, size_t ws_size,
                              hipStream_t stream) {
    const float* x = (const float*)d_in[0];
    const float* w = (const float*)d_in[1];
    float* out = (float*)d_out;
    (void)in_sizes; (void)n_in; (void)out_size; (void)d_ws; (void)ws_size;

    dim3 grid(L_ / TL, B_);   // (64, 32) = 2048 blocks
    dim3 block(F_);           // 256 threads, one per feature column
    hipLaunchKernelGGL(fan_kernel, grid, block, 0, stream, x, w, out);
}